// Round 12
// baseline (276.242 us; speedup 1.0000x reference)
//
#include <hip/hip_runtime.h>
#include <cmath>

#define DIM 128
#define NHALF 4096
#define NROWS 8192
#define NTILES 8256   // 128*129/2 upper-triangle 64x64 tiles
#define NSIMEXP 2064  // NTILES/4 simexp blocks
#define NFINAL 64     // tail blocks doing finalize (4 chunks of 32 rows each)
// FRAG_SCALE^2 = log2(e)/tau = 1.4426950408889634/0.5
#define FRAG_SCALE 1.69864368f

typedef __attribute__((ext_vector_type(8))) short bf16x8;
typedef __attribute__((ext_vector_type(4))) float f32x4;

static __device__ __forceinline__ unsigned short f32_to_bf16(float f) {
  unsigned int u = __float_as_uint(f);
  u = (u + 0x7FFFu + ((u >> 16) & 1u)) >> 16;
  return (unsigned short)u;
}

// VALU-pipe cross-lane add via DPP row rotate (16-lane rows on gfx9/CDNA).
// dpp_ctrl must be a literal constant -> template parameter.
template <int CTRL>
static __device__ __forceinline__ float dpp_radd(float v) {
  int t = __builtin_amdgcn_update_dpp(0, __float_as_int(v), CTRL, 0xF, 0xF,
                                      false);
  return v + __int_as_float(t);
}
static __device__ __forceinline__ float row16_allreduce(float v) {
  v = dpp_radd<0x121>(v);  // row_ror:1
  v = dpp_radd<0x122>(v);  // row_ror:2
  v = dpp_radd<0x124>(v);  // row_ror:4
  v = dpp_radd<0x128>(v);  // row_ror:8
  return v;
}

// Fragment-major layout of the normalized bf16 matrix A_f:
//   group g = row>>4 (0..511), page = g*4 + kc (1 KB each).
//   Within a page: 16B chunk at offset (q*16 + n)*16 holds
//   row g*16+n, cols kc*32 + q*8 .. +8.
// Every MFMA fragment load is `base + lane*16` -> 64 lanes x 16 B fully
// contiguous (ideal coalescing; no 16-way gather).

// One wave per pair r in [0,4096): L2-normalize z_i[r], z_j[r], scale by
// sqrt(log2e/tau), write bf16 rows r and r+4096 in fragment-major order;
// pos[r]=pos[r+4096] = dot/(|zi||zj|)/tau in fp32. Also zeroes out[0] and
// the simexp completion counter (graph replay re-poisons the workspace).
__global__ __launch_bounds__(256) void prep_kernel(
    const float* __restrict__ z_i, const float* __restrict__ z_j,
    unsigned int* __restrict__ A, float* __restrict__ pos,
    float* __restrict__ out, unsigned int* __restrict__ counter) {
  int wave = threadIdx.x >> 6;
  int lane = threadIdx.x & 63;
  int r = blockIdx.x * 4 + wave;
  if (blockIdx.x == 0 && threadIdx.x == 0) {
    out[0] = 0.0f;
    counter[0] = 0u;
  }
  float2 a = *(const float2*)(z_i + (size_t)r * DIM + 2 * lane);
  float2 b = *(const float2*)(z_j + (size_t)r * DIM + 2 * lane);
  float sa = a.x * a.x + a.y * a.y;
  float sb = b.x * b.x + b.y * b.y;
  float dp = a.x * b.x + a.y * b.y;
#pragma unroll
  for (int off = 1; off < 64; off <<= 1) {
    sa += __shfl_xor(sa, off);
    sb += __shfl_xor(sb, off);
    dp += __shfl_xor(dp, off);
  }
  float na = fmaxf(sqrtf(sa), 1e-8f);
  float nb = fmaxf(sqrtf(sb), 1e-8f);
  float si = FRAG_SCALE / na;
  float sj = FRAG_SCALE / nb;
  unsigned int pa = (unsigned int)f32_to_bf16(a.x * si) |
                    ((unsigned int)f32_to_bf16(a.y * si) << 16);
  unsigned int pb = (unsigned int)f32_to_bf16(b.x * sj) |
                    ((unsigned int)f32_to_bf16(b.y * sj) << 16);
  // fragment-major scatter store (lane holds cols 2*lane, 2*lane+1):
  // kc = lane>>4, q = (lane>>2)&3, byte-quad bq = lane&3, n = r&15.
  int rg = r >> 4;
  int n = r & 15;
  int kc = lane >> 4;
  int q = (lane >> 2) & 3;
  int bq = lane & 3;
  int off4 = rg * 1024 + kc * 256 + q * 64 + n * 4 + bq;
  A[off4] = pa;
  A[off4 + 262144] = pb;  // z_j groups start at group 256
  if (lane == 0) {
    float p = dp / (na * nb) * 2.0f;  // /tau, tau=0.5
    pos[r] = p;
    pos[r + NHALF] = p;
  }
}

// One wave = one independent 64x64 upper-triangle tile (ti<=tj over 128
// bands of 64 rows). No LDS, no barriers, no atomics in the hot path;
// fragment loads fully coalesced (fragment-major A); 4 waves/SIMD of TLP.
// Row exp-sums reduce on the VALU pipe via DPP row_ror; disjoint-slot
// stores into partials[128][8192] (row slot tj-ti, col slot 128-(tj-ti);
// per band each slot written exactly once -> no zero-init, no collisions).
static __device__ __forceinline__ void simexp_body(
    int g, int lane, const unsigned int* __restrict__ Au,
    float* __restrict__ partials) {
  const int q = lane >> 4;
  const int n = lane & 15;

  // decode wave-tile index g -> (ti, tj), ti <= tj < 128
  int ti = (int)((257.0f - sqrtf(66049.0f - 8.0f * (float)g)) * 0.5f);
  int start = 128 * ti - (ti * (ti - 1)) / 2;
  if (g < start) {
    ti--;
    start = 128 * ti - (ti * (ti - 1)) / 2;
  } else if (g >= start + (128 - ti)) {
    start += 128 - ti;
    ti++;
  }
  int tj = ti + (g - start);
  const bool diag = (ti == tj);

  // fragment base: page p -> 64 chunks of 16B; this lane's chunk p*64+lane
  const bf16x8* frag = (const bf16x8*)Au + lane;

  f32x4 acc[16];
#pragma unroll
  for (int i = 0; i < 16; i++)
#pragma unroll
    for (int j = 0; j < 4; j++) acc[i][j] = 0.0f;

#pragma unroll
  for (int kc = 0; kc < 4; kc++) {
    bf16x8 af[4], bfr[4];
#pragma unroll
    for (int mi = 0; mi < 4; mi++)
      af[mi] = frag[(size_t)(ti * 16 + mi * 4 + kc) * 64];
#pragma unroll
    for (int ni = 0; ni < 4; ni++)
      bfr[ni] = frag[(size_t)(tj * 16 + ni * 4 + kc) * 64];
#pragma unroll
    for (int mi = 0; mi < 4; mi++)
#pragma unroll
      for (int ni = 0; ni < 4; ni++)
        acc[mi * 4 + ni] = __builtin_amdgcn_mfma_f32_16x16x32_bf16(
            af[mi], bfr[ni], acc[mi * 4 + ni], 0, 0, 0);
  }

  // epilogue: exp2, (diag-only) mask, row + column accumulation in regs
  float eaccR[16];
  float eaccC[4];
#pragma unroll
  for (int i = 0; i < 16; i++) eaccR[i] = 0.0f;
#pragma unroll
  for (int i = 0; i < 4; i++) eaccC[i] = 0.0f;
  if (diag) {
#pragma unroll
    for (int mi = 0; mi < 4; mi++)
#pragma unroll
      for (int ni = 0; ni < 4; ni++)
#pragma unroll
        for (int rg = 0; rg < 4; rg++) {
          float e = __builtin_amdgcn_exp2f(acc[mi * 4 + ni][rg]);
          // local row/col within tile; ti==tj so global offsets cancel
          e = ((mi * 16 + q * 4 + rg) == (ni * 16 + n)) ? 0.0f : e;
          eaccR[mi * 4 + rg] += e;
          eaccC[ni] += e;
        }
  } else {
#pragma unroll
    for (int mi = 0; mi < 4; mi++)
#pragma unroll
      for (int ni = 0; ni < 4; ni++)
#pragma unroll
        for (int rg = 0; rg < 4; rg++) {
          float e = __builtin_amdgcn_exp2f(acc[mi * 4 + ni][rg]);
          eaccR[mi * 4 + rg] += e;
          eaccC[ni] += e;
        }
  }

  const int dslot = tj - ti;
  // row sums: DPP allreduce within each 16-lane group (VALU pipe), store
  float* prow = partials + (size_t)dslot * NROWS + ti * 64;
#pragma unroll
  for (int mi = 0; mi < 4; mi++) {
#pragma unroll
    for (int rg = 0; rg < 4; rg++) {
      float v = row16_allreduce(eaccR[mi * 4 + rg]);
      if (n == 0) prow[mi * 16 + q * 4 + rg] = v;
    }
  }
  // column sums (symmetry credit): reduce across q (xor 16,32), store
  if (!diag) {
    float* pcol = partials + (size_t)(128 - dslot) * NROWS + tj * 64;
#pragma unroll
    for (int ni = 0; ni < 4; ni++) {
      float v = eaccC[ni];
      v += __shfl_xor(v, 16);
      v += __shfl_xor(v, 32);
      if (lane < 16) pcol[ni * 16 + lane] = v;
    }
  }
}

// one 32-row chunk: rowsum = sum of 128 partial slots (8-way k-split
// across the block), loss contribution log(rowsum) - pos, one atomicAdd.
static __device__ __forceinline__ void finalize_body(
    int chunk, int tid, const float* __restrict__ partials,
    const float* __restrict__ pos, float* __restrict__ out,
    float red[8][32]) {
  int rr = tid & 31;
  int ks = tid >> 5;  // 0..7
  int r = chunk * 32 + rr;
  float s = 0.0f;
#pragma unroll
  for (int k = 0; k < 16; k++)
    s += partials[(size_t)(ks * 16 + k) * NROWS + r];
  red[ks][rr] = s;
  __syncthreads();
  if (tid < 32) {
    float t = 0.0f;
#pragma unroll
    for (int k2 = 0; k2 < 8; k2++) t += red[k2][tid];
    float local = logf(t) - pos[chunk * 32 + tid];
#pragma unroll
    for (int off = 1; off < 32; off <<= 1) local += __shfl_xor(local, off);
    if (tid == 0) atomicAdd(out, local * (1.0f / (float)NROWS));
  }
}

// Fused simexp + finalize: blocks [0,NSIMEXP) compute tiles, then
// threadfence -> syncthreads -> one device-scope counter increment.
// Blocks [NSIMEXP, NSIMEXP+NFINAL) -- dispatched last, far below the
// ~1024-block residency cap so no deadlock is possible -- spin on the
// counter with acquire loads + s_sleep, then each reduces 4 chunks of 32
// rows. Removes one kernel launch+drain boundary and overlaps finalize
// with the simexp tail. (Grid-wide coop sync measured 400+ us on this
// 8-XCD part -- this one-way ticket costs ~nothing.)
__global__ __launch_bounds__(256, 4) void simexp_kernel(
    const unsigned int* __restrict__ Au, float* __restrict__ partials,
    const float* __restrict__ pos, float* __restrict__ out,
    unsigned int* __restrict__ counter) {
  const int tid = threadIdx.x;
  __shared__ float red[8][32];

  if (blockIdx.x >= NSIMEXP) {
    // finalize tail block
    if (tid == 0) {
      while (__hip_atomic_load(counter, __ATOMIC_ACQUIRE,
                               __HIP_MEMORY_SCOPE_AGENT) < NSIMEXP)
        __builtin_amdgcn_s_sleep(2);
    }
    __syncthreads();
    __threadfence();  // all simexp stores device-visible (release->acquire)
    int fb = blockIdx.x - NSIMEXP;
#pragma unroll
    for (int i = 0; i < 4; i++) {
      finalize_body(fb * 4 + i, tid, partials, pos, out, red);
      __syncthreads();
    }
    return;
  }

  const int lane = tid & 63;
  const int w = tid >> 6;
  simexp_body(blockIdx.x * 4 + w, lane, Au, partials);

  __threadfence();  // make this thread's partials stores device-visible
  __syncthreads();  // all threads' fences done
  if (tid == 0) atomicAdd(counter, 1u);  // device-scope (m20)
}

extern "C" void kernel_launch(void* const* d_in, const int* in_sizes, int n_in,
                              void* d_out, int out_size, void* d_ws,
                              size_t ws_size, hipStream_t stream) {
  const float* z_i = (const float*)d_in[0];
  const float* z_j = (const float*)d_in[1];
  float* out = (float*)d_out;

  unsigned int* A = (unsigned int*)d_ws;                 // fragment-major, 2 MB
  float* partials = (float*)((char*)d_ws + (1u << 21));  // 128*8192 f32 = 4 MB
  float* pos = (float*)((char*)d_ws + (3u << 21));       // 32 KB
  unsigned int* counter =
      (unsigned int*)((char*)d_ws + (3u << 21) + 32768);  // 4 B ticket

  prep_kernel<<<NHALF / 4, 256, 0, stream>>>(z_i, z_j, A, pos, out, counter);
  simexp_kernel<<<NSIMEXP + NFINAL, 256, 0, stream>>>(
      (const unsigned int*)A, partials, pos, out, counter);
}

// Round 13
// 80.480 us; speedup vs baseline: 3.4325x; 3.4325x over previous
//
#include <hip/hip_runtime.h>
#include <cmath>

#define DIM 128
#define NHALF 4096
#define NROWS 8192
#define NTILES 8256  // 128*129/2 upper-triangle 64x64 tiles
// FRAG_SCALE^2 = log2(e)/tau = 1.4426950408889634/0.5
#define FRAG_SCALE 1.69864368f

typedef __attribute__((ext_vector_type(8))) short bf16x8;
typedef __attribute__((ext_vector_type(4))) float f32x4;

static __device__ __forceinline__ unsigned short f32_to_bf16(float f) {
  unsigned int u = __float_as_uint(f);
  u = (u + 0x7FFFu + ((u >> 16) & 1u)) >> 16;
  return (unsigned short)u;
}

// VALU-pipe cross-lane add via DPP row rotate (16-lane rows on gfx9/CDNA).
// dpp_ctrl must be a literal constant -> template parameter.
template <int CTRL>
static __device__ __forceinline__ float dpp_radd(float v) {
  int t = __builtin_amdgcn_update_dpp(0, __float_as_int(v), CTRL, 0xF, 0xF,
                                      false);
  return v + __int_as_float(t);
}
static __device__ __forceinline__ float row16_allreduce(float v) {
  v = dpp_radd<0x121>(v);  // row_ror:1
  v = dpp_radd<0x122>(v);  // row_ror:2
  v = dpp_radd<0x124>(v);  // row_ror:4
  v = dpp_radd<0x128>(v);  // row_ror:8
  return v;
}

// Fragment-major layout of the normalized bf16 matrix A_f:
//   group g = row>>4 (0..511), page = g*4 + kc (1 KB each).
//   Within a page: 16B chunk at offset (q*16 + n)*16 holds
//   row g*16+n, cols kc*32 + q*8 .. +8.
// Every MFMA fragment load is `base + lane*16` -> 64 lanes x 16 B fully
// contiguous (ideal coalescing; no 16-way gather).

// One wave per pair r in [0,4096): L2-normalize z_i[r], z_j[r], scale by
// sqrt(log2e/tau), write bf16 rows r and r+4096 in fragment-major order;
// pos[r]=pos[r+4096] = dot/(|zi||zj|)/tau in fp32. Also zeroes out[0].
// 64-lane reduce: DPP within 16-lane rows (short VALU chain), shfl for the
// cross-row steps (16, 32).
__global__ __launch_bounds__(256) void prep_kernel(
    const float* __restrict__ z_i, const float* __restrict__ z_j,
    unsigned int* __restrict__ A, float* __restrict__ pos,
    float* __restrict__ out) {
  int wave = threadIdx.x >> 6;
  int lane = threadIdx.x & 63;
  int r = blockIdx.x * 4 + wave;
  if (blockIdx.x == 0 && threadIdx.x == 0) out[0] = 0.0f;
  float2 a = *(const float2*)(z_i + (size_t)r * DIM + 2 * lane);
  float2 b = *(const float2*)(z_j + (size_t)r * DIM + 2 * lane);
  float sa = a.x * a.x + a.y * a.y;
  float sb = b.x * b.x + b.y * b.y;
  float dp = a.x * b.x + a.y * b.y;
  sa = row16_allreduce(sa);
  sb = row16_allreduce(sb);
  dp = row16_allreduce(dp);
#pragma unroll
  for (int off = 16; off < 64; off <<= 1) {
    sa += __shfl_xor(sa, off);
    sb += __shfl_xor(sb, off);
    dp += __shfl_xor(dp, off);
  }
  float na = fmaxf(sqrtf(sa), 1e-8f);
  float nb = fmaxf(sqrtf(sb), 1e-8f);
  float si = FRAG_SCALE / na;
  float sj = FRAG_SCALE / nb;
  unsigned int pa = (unsigned int)f32_to_bf16(a.x * si) |
                    ((unsigned int)f32_to_bf16(a.y * si) << 16);
  unsigned int pb = (unsigned int)f32_to_bf16(b.x * sj) |
                    ((unsigned int)f32_to_bf16(b.y * sj) << 16);
  // fragment-major scatter store (lane holds cols 2*lane, 2*lane+1):
  // kc = lane>>4, q = (lane>>2)&3, byte-quad bq = lane&3, n = r&15.
  int rg = r >> 4;
  int n = r & 15;
  int kc = lane >> 4;
  int q = (lane >> 2) & 3;
  int bq = lane & 3;
  int off4 = rg * 1024 + kc * 256 + q * 64 + n * 4 + bq;
  A[off4] = pa;
  A[off4 + 262144] = pb;  // z_j groups start at group 256
  if (lane == 0) {
    float p = dp / (na * nb) * 2.0f;  // /tau, tau=0.5
    pos[r] = p;
    pos[r + NHALF] = p;
  }
}

// One wave = one independent 64x64 upper-triangle tile (ti<=tj over 128
// bands of 64 rows). No LDS, no barriers, no atomics; fragment loads fully
// coalesced (fragment-major A). launch_bounds(256,3) gives the compiler
// ~170 regs: room to keep 2 kc-batches of fragment loads in flight and
// halve the serialized L2 waits per tile (R7's 64-VGPR build serialized
// them). Row exp-sums reduce on the VALU pipe via DPP row_ror;
// disjoint-slot stores into partials[128][8192] (row slot tj-ti, col slot
// 128-(tj-ti); per band each slot written exactly once).
__global__ __launch_bounds__(256, 3) void simexp_kernel(
    const unsigned int* __restrict__ Au, float* __restrict__ partials) {
  const int lane = threadIdx.x & 63;
  const int w = threadIdx.x >> 6;
  const int q = lane >> 4;
  const int n = lane & 15;

  // decode wave-tile index g -> (ti, tj), ti <= tj < 128
  int g = blockIdx.x * 4 + w;
  int ti = (int)((257.0f - sqrtf(66049.0f - 8.0f * (float)g)) * 0.5f);
  int start = 128 * ti - (ti * (ti - 1)) / 2;
  if (g < start) {
    ti--;
    start = 128 * ti - (ti * (ti - 1)) / 2;
  } else if (g >= start + (128 - ti)) {
    start += 128 - ti;
    ti++;
  }
  int tj = ti + (g - start);
  const bool diag = (ti == tj);

  // fragment base: page p -> 64 chunks of 16B; this lane's chunk p*64+lane
  const bf16x8* frag = (const bf16x8*)Au + lane;

  f32x4 acc[16];
#pragma unroll
  for (int i = 0; i < 16; i++)
#pragma unroll
    for (int j = 0; j < 4; j++) acc[i][j] = 0.0f;

#pragma unroll
  for (int kc = 0; kc < 4; kc++) {
    bf16x8 af[4], bfr[4];
#pragma unroll
    for (int mi = 0; mi < 4; mi++)
      af[mi] = frag[(size_t)(ti * 16 + mi * 4 + kc) * 64];
#pragma unroll
    for (int ni = 0; ni < 4; ni++)
      bfr[ni] = frag[(size_t)(tj * 16 + ni * 4 + kc) * 64];
#pragma unroll
    for (int mi = 0; mi < 4; mi++)
#pragma unroll
      for (int ni = 0; ni < 4; ni++)
        acc[mi * 4 + ni] = __builtin_amdgcn_mfma_f32_16x16x32_bf16(
            af[mi], bfr[ni], acc[mi * 4 + ni], 0, 0, 0);
  }

  // epilogue: exp2, (diag-only) mask, row + column accumulation in regs
  float eaccR[16];
  float eaccC[4];
#pragma unroll
  for (int i = 0; i < 16; i++) eaccR[i] = 0.0f;
#pragma unroll
  for (int i = 0; i < 4; i++) eaccC[i] = 0.0f;
  if (diag) {
#pragma unroll
    for (int mi = 0; mi < 4; mi++)
#pragma unroll
      for (int ni = 0; ni < 4; ni++)
#pragma unroll
        for (int rg = 0; rg < 4; rg++) {
          float e = __builtin_amdgcn_exp2f(acc[mi * 4 + ni][rg]);
          // local row/col within tile; ti==tj so global offsets cancel
          e = ((mi * 16 + q * 4 + rg) == (ni * 16 + n)) ? 0.0f : e;
          eaccR[mi * 4 + rg] += e;
          eaccC[ni] += e;
        }
  } else {
#pragma unroll
    for (int mi = 0; mi < 4; mi++)
#pragma unroll
      for (int ni = 0; ni < 4; ni++)
#pragma unroll
        for (int rg = 0; rg < 4; rg++) {
          float e = __builtin_amdgcn_exp2f(acc[mi * 4 + ni][rg]);
          eaccR[mi * 4 + rg] += e;
          eaccC[ni] += e;
        }
  }

  const int dslot = tj - ti;
  // row sums: DPP allreduce within each 16-lane group (VALU pipe), store
  float* prow = partials + (size_t)dslot * NROWS + ti * 64;
#pragma unroll
  for (int mi = 0; mi < 4; mi++) {
#pragma unroll
    for (int rg = 0; rg < 4; rg++) {
      float v = row16_allreduce(eaccR[mi * 4 + rg]);
      if (n == 0) prow[mi * 16 + q * 4 + rg] = v;
    }
  }
  // column sums (symmetry credit): reduce across q (xor 16,32), store
  if (!diag) {
    float* pcol = partials + (size_t)(128 - dslot) * NROWS + tj * 64;
#pragma unroll
    for (int ni = 0; ni < 4; ni++) {
      float v = eaccC[ni];
      v += __shfl_xor(v, 16);
      v += __shfl_xor(v, 32);
      if (lane < 16) pcol[ni * 16 + lane] = v;
    }
  }
}

// loss = mean over rows of log(rowsum) - pos; rowsum = sum of the row's
// 128 partial slots. 256 blocks x 256 threads: block handles 32 rows with
// an 8-way k-split (tid = ks*32 + rr), LDS reduce, one atomic per block.
__global__ __launch_bounds__(256) void finalize_kernel(
    const float* __restrict__ partials, const float* __restrict__ pos,
    float* __restrict__ out) {
  int tid = threadIdx.x;
  int rr = tid & 31;
  int ks = tid >> 5;  // 0..7
  int r = blockIdx.x * 32 + rr;
  float s = 0.0f;
#pragma unroll
  for (int k = 0; k < 16; k++)
    s += partials[(size_t)(ks * 16 + k) * NROWS + r];
  __shared__ float red[8][32];
  red[ks][rr] = s;
  __syncthreads();
  if (tid < 32) {
    float t = 0.0f;
#pragma unroll
    for (int k2 = 0; k2 < 8; k2++) t += red[k2][tid];
    float local = logf(t) - pos[blockIdx.x * 32 + tid];
#pragma unroll
    for (int off = 1; off < 32; off <<= 1) local += __shfl_xor(local, off);
    if (tid == 0) atomicAdd(out, local * (1.0f / (float)NROWS));
  }
}

extern "C" void kernel_launch(void* const* d_in, const int* in_sizes, int n_in,
                              void* d_out, int out_size, void* d_ws,
                              size_t ws_size, hipStream_t stream) {
  const float* z_i = (const float*)d_in[0];
  const float* z_j = (const float*)d_in[1];
  float* out = (float*)d_out;

  unsigned int* A = (unsigned int*)d_ws;                 // fragment-major, 2 MB
  float* partials = (float*)((char*)d_ws + (1u << 21));  // 128*8192 f32 = 4 MB
  float* pos = (float*)((char*)d_ws + (3u << 21));       // 32 KB

  prep_kernel<<<NHALF / 4, 256, 0, stream>>>(z_i, z_j, A, pos, out);
  simexp_kernel<<<NTILES / 4, 256, 0, stream>>>((const unsigned int*)A,
                                                partials);
  finalize_kernel<<<NROWS / 32, 256, 0, stream>>>(partials, pos, out);
}